// Round 8
// baseline (373.484 us; speedup 1.0000x reference)
//
#include <hip/hip_runtime.h>
#include <hip/hip_cooperative_groups.h>

namespace cg = cooperative_groups;

// ---------- common helpers ----------
typedef __attribute__((ext_vector_type(8))) unsigned short ushort8v;
typedef __attribute__((ext_vector_type(4))) unsigned short ushort4v;
typedef __attribute__((ext_vector_type(8))) __bf16 bf16x8;
typedef __attribute__((ext_vector_type(4))) float floatx4;

__device__ __forceinline__ unsigned short f2b(float f) {
    unsigned u = __float_as_uint(f);
    unsigned r = u + 0x7fffu + ((u >> 16) & 1u);   // RNE
    return (unsigned short)(r >> 16);
}
__device__ __forceinline__ float b2f(unsigned short h) {
    return __uint_as_float(((unsigned)h) << 16);
}
__device__ __forceinline__ void gload16(const void* g, void* l) {
    __builtin_amdgcn_global_load_lds(
        (const __attribute__((address_space(1))) unsigned int*)g,
        (__attribute__((address_space(3))) unsigned int*)l,
        16, 0, 0);
}

#define VMW(N) asm volatile("s_waitcnt vmcnt(" #N ")" ::: "memory")

// ============================================================================
// R16: COOPERATIVE MEGA-KERNEL. Ledger across R0-R15: total - gemm1 = 130-153us
// every round, insensitive to pp/prep optimization (R15: -1.1us), never visible
// in top-5 (cutoff ~45). BW-bound estimates for prep/pp/gemm2 sum to ~60us ->
// either all phases run 2x over roofline or dispatch gaps dominate. 4 separate
// dispatches cannot distinguish these. This round fuses everything into one
// hipLaunchCooperativeKernel (harness-supported per guide) with 3 grid.sync():
// gaps eliminated + single profiled dispatch = true GPU time + aggregate PMC.
//  P1 prep  : verified R6 x-map / R7 W-store / softmax, remapped to 256x512.
//  P2 gemm1 : R7 gemm_m1 VERBATIM (256 blocks, 8 waves, 3-buf counted vmcnt).
//  P3 pp    : full 10-level register walk (R7's verified backward-walk
//             construction, same f32 multiply order -> bitwise-identical);
//             no pa/pb LDS, 1 barrier; lane->row-fast map = 1KB-contig stores.
//  P4 gemm2 : R7 gemm_p4 as TWO concurrent 4-wave tile-groups (vmcnt is
//             per-wave; barriers align; LDS 2x64KB=128KB <= 160KB).
// Fragment-swizzled layout: tensor [T16][KC][16][8] bf16;
//   elem (t16, kc, l, e) = Mat[t16*16 + l][kc*8 + e]
// ============================================================================

// ---- gemm1 step: 256x128 tile, 8 waves, 3 rotating buffers, counted vmcnt ----
#define M1_STEP(ks_, CUR_, STG_, VM_, DOSTAGE_)                                       \
    {                                                                                 \
        if (DOSTAGE_) STAGE((ks_) + 2, (STG_));                                       \
        VMW(VM_);                                                                     \
        __builtin_amdgcn_s_barrier();                                                 \
        const unsigned short* lA = &lds1[(CUR_)][0];                                  \
        const unsigned short* lB = &lds1[(CUR_)][8192];                               \
        bf16x8 af[4], bv[4];                                                          \
        _Pragma("unroll")                                                             \
        for (int m2 = 0; m2 < 4; m2++)                                                \
            af[m2] = __builtin_bit_cast(bf16x8,                                       \
                *(const ushort8v*)&lA[((wr * 4 + m2) * 4 + quad) * 128 + l16 * 8]);   \
        _Pragma("unroll")                                                             \
        for (int n2 = 0; n2 < 4; n2++)                                                \
            bv[n2] = __builtin_bit_cast(bf16x8,                                       \
                *(const ushort8v*)&lB[((wc * 4 + n2) * 4 + quad) * 128 + l16 * 8]);   \
        asm volatile("s_waitcnt lgkmcnt(0)" ::: "memory");                            \
        __builtin_amdgcn_sched_barrier(0);                                            \
        __builtin_amdgcn_s_setprio(1);                                                \
        _Pragma("unroll")                                                             \
        for (int m2 = 0; m2 < 4; m2++)                                                \
            _Pragma("unroll")                                                         \
            for (int n2 = 0; n2 < 4; n2++)                                            \
                acc[m2][n2] = __builtin_amdgcn_mfma_f32_16x16x32_bf16(                \
                    af[m2], bv[n2], acc[m2][n2], 0, 0, 0);                            \
        __builtin_amdgcn_s_setprio(0);                                                \
        __builtin_amdgcn_s_barrier();                                                 \
    }

// ---- gemm2 step: 128x128 tile per 4-wave group, 4 buffers, counted vmcnt ----
#define G2_STEP(ks_, b_, VM_, DOSTAGE_)                                             \
    {                                                                               \
        VMW(VM_);                                                                   \
        __builtin_amdgcn_s_barrier();                                               \
        __builtin_amdgcn_sched_barrier(0);                                          \
        const unsigned short* lA = ldsg + (b_) * 8192;                              \
        const unsigned short* lB = lA + 4096;                                       \
        bf16x8 af[4], bv[4];                                                        \
        _Pragma("unroll")                                                           \
        for (int m2 = 0; m2 < 4; m2++)                                              \
            af[m2] = __builtin_bit_cast(bf16x8,                                     \
                *(const ushort8v*)&lA[((wr2 * 4 + m2) * 4 + quad) * 128 + l16 * 8]);\
        _Pragma("unroll")                                                           \
        for (int n2 = 0; n2 < 4; n2++)                                              \
            bv[n2] = __builtin_bit_cast(bf16x8,                                     \
                *(const ushort8v*)&lB[((wc2 * 4 + n2) * 4 + quad) * 128 + l16 * 8]);\
        asm volatile("s_waitcnt lgkmcnt(0)" ::: "memory");                          \
        __builtin_amdgcn_sched_barrier(0);                                          \
        __builtin_amdgcn_s_barrier();                                               \
        __builtin_amdgcn_sched_barrier(0);                                          \
        if (DOSTAGE_) STG2((ks_) + 4, (b_));                                        \
        __builtin_amdgcn_s_setprio(1);                                              \
        _Pragma("unroll")                                                           \
        for (int m2 = 0; m2 < 4; m2++)                                              \
            _Pragma("unroll")                                                       \
            for (int n2 = 0; n2 < 4; n2++)                                          \
                acc[m2][n2] = __builtin_amdgcn_mfma_f32_16x16x32_bf16(              \
                    af[m2], bv[n2], acc[m2][n2], 0, 0, 0);                          \
        __builtin_amdgcn_s_setprio(0);                                              \
    }

__global__ __launch_bounds__(512, 1) void mega(const float* __restrict__ x,
                                               const float* __restrict__ W,
                                               const float* __restrict__ bias,
                                               const float* __restrict__ ldd,
                                               float* __restrict__ out,
                                               unsigned short* __restrict__ A2x,
                                               unsigned short* __restrict__ B2w,
                                               unsigned short* __restrict__ dec,
                                               unsigned short* __restrict__ B2p,
                                               unsigned short* __restrict__ A2p) {
    __shared__ __align__(16) unsigned char smem[131072];   // 128KB union, 1 block/CU
    cg::grid_group grid = cg::this_grid();

    const int t   = threadIdx.x;               // 0..511
    const int bid = blockIdx.x;                // 0..255
    const int lane = t & 63;
    const int wave = t >> 6;                   // 0..7
    const int quad = lane >> 4, l16 = lane & 15;

    // ======================= P1: prep =======================
    // --- x cvt+swizzle: 1024 units (16-row slab halves), 4/block ---
    {
        const int xl16 = t & 15, kcol = t >> 4;           // kcol 0..31
        for (int uu = 0; uu < 4; uu++) {
            const int u  = bid * 4 + uu;                  // 0..1023
            const int mt = u >> 1, h = u & 1;
            const float* xr0 = x + (size_t)(mt * 16 + xl16) * 2048;
#pragma unroll
            for (int i = 0; i < 4; i++) {
                const int kc = h * 128 + i * 32 + kcol;
                const float* xr = xr0 + kc * 8;
                float4 v0 = *(const float4*)xr;
                float4 v1 = *(const float4*)(xr + 4);
                ushort8v o;
                o[0] = f2b(v0.x); o[1] = f2b(v0.y); o[2] = f2b(v0.z); o[3] = f2b(v0.w);
                o[4] = f2b(v1.x); o[5] = f2b(v1.y); o[6] = f2b(v1.z); o[7] = f2b(v1.w);
                *(ushort8v*)(A2x + ((size_t)(mt * 256 + kc) * 16 + xl16) * 8) = o;
            }
        }
    }
    // --- W transpose+swizzle: 2048 units (32x32 tiles), 8/block, 2 parallel ---
    {
        const int sub = t >> 8, tt = t & 255;
        float* tl = (float*)smem + sub * (32 * 33);
        const int tx = tt & 31, ty = tt >> 5;             // ty 0..7
        for (int it = 0; it < 4; it++) {
            const int idx = bid * 8 + it * 2 + sub;       // 0..2047
            const int n0 = (idx & 31) * 32, k0 = (idx >> 5) * 32;
            __syncthreads();
#pragma unroll
            for (int i = 0; i < 4; i++) {
                int k = k0 + ty + i * 8, n = n0 + tx;
                tl[(ty + i * 8) * 33 + tx] = (n < 1023) ? W[(size_t)k * 1023 + n] : 0.f;
            }
            __syncthreads();
            {
                const int n = n0 + tx;                    // tx2 == tx
                const int k = k0 + ty * 4;
                ushort4v o;
#pragma unroll
                for (int e = 0; e < 4; e++) o[e] = f2b(tl[(ty * 4 + e) * 33 + tx]);
                size_t off = ((size_t)((n >> 4) * 256 + (k >> 3)) * 16 + (n & 15)) * 8 + (k & 7);
                *(ushort4v*)(B2w + off) = o;
            }
        }
    }
    // --- softmax(leaf_dist): 1024 units, 4/block, 2 parallel ---
    {
        const int sub = t >> 8, tt = t & 255;
        float* bf = (float*)smem + sub * 1024;
        float* rd = (float*)smem + 2048 + sub * 8;
        for (int it = 0; it < 2; it++) {
            const int l0 = bid * 4 + it * 2 + sub;        // 0..1023
            const float* r = ldd + (size_t)l0 * 1000;
            __syncthreads();
            float mx = -3.4e38f;
            for (int i = tt; i < 1000; i += 256) { float v = r[i]; bf[i] = v; mx = fmaxf(mx, v); }
#pragma unroll
            for (int o = 32; o > 0; o >>= 1) mx = fmaxf(mx, __shfl_down(mx, o));
            if ((tt & 63) == 0) rd[tt >> 6] = mx;
            __syncthreads();
            mx = fmaxf(fmaxf(rd[0], rd[1]), fmaxf(rd[2], rd[3]));
            float s = 0.f;
            for (int i = tt; i < 1000; i += 256) { float e = __expf(bf[i] - mx); bf[i] = e; s += e; }
#pragma unroll
            for (int o = 32; o > 0; o >>= 1) s += __shfl_down(s, o);
            if ((tt & 63) == 0) rd[4 + (tt >> 6)] = s;
            __syncthreads();
            float inv = 1.f / (rd[4] + rd[5] + rd[6] + rd[7]);
            for (int i = tt; i < 1024; i += 256) {
                float pv = (i < 1000) ? bf[i] * inv : 0.f;
                size_t off = ((size_t)((i >> 4) * 128 + (l0 >> 3)) * 16 + (i & 15)) * 8 + (l0 & 7);
                B2p[off] = f2b(pv);
            }
        }
    }
    grid.sync();

    // ======================= P2: gemm1 (verbatim R7 gemm_m1) =======================
    {
        constexpr int KC = 256;
        unsigned short (*lds1)[12288] = (unsigned short(*)[12288])smem;  // 3x24KB = 72KB

        const int wr = wave >> 1, wc = wave & 1;   // 4M x 2N, 64x64/wave

        const int xcd = bid & 7;
        const int j   = bid >> 3;                  // 0..31
        const int bm  = xcd * 4 + (j & 3);         // 0..31 (256-row tiles)
        const int bn  = j >> 2;                    // 0..7  (128-col tiles)

        const int cA  = t >> 4;                    // 0..31
        const int sub = (t & 15) * 8;
        const unsigned short* gA0 = A2x + ((size_t)(bm * 16 + (cA >> 2))        * KC + (cA & 3)) * 128 + sub;
        const unsigned short* gA1 = A2x + ((size_t)(bm * 16 + ((cA + 32) >> 2)) * KC + (cA & 3)) * 128 + sub;
        const unsigned short* gB0 = B2w + ((size_t)(bn * 8  + (cA >> 2))        * KC + (cA & 3)) * 128 + sub;
        const int dA0 = cA * 128 + sub;
        const int dA1 = (cA + 32) * 128 + sub;
        const int dB0 = 8192 + cA * 128 + sub;

        floatx4 acc[4][4] = {};
        constexpr int nks = KC / 4;                // 64 steps (BK=32)

        auto STAGE = [&](int ks, int b) {
            const size_t ko = (size_t)ks * 512;
            gload16(gA0 + ko, &lds1[b][dA0]);
            gload16(gA1 + ko, &lds1[b][dA1]);
            gload16(gB0 + ko, &lds1[b][dB0]);
        };

        STAGE(0, 0); STAGE(1, 1);
        int c0 = 0, c1 = 1, c2 = 2;
        for (int ks = 0; ks < nks - 2; ++ks) {
            M1_STEP(ks, c0, c2, 6, true);
            int tmp = c0; c0 = c1; c1 = c2; c2 = tmp;
        }
        M1_STEP(nks - 2, c0, c2, 3, false);
        { int tmp = c0; c0 = c1; c1 = c2; c2 = tmp; }
        M1_STEP(nks - 1, c0, c2, 0, false);

        const int mt0 = bm * 16 + wr * 4;
        const int nt0 = bn * 8  + wc * 4;
#pragma unroll
        for (int n2 = 0; n2 < 4; n2++) {
            const int col = (nt0 + n2) * 16 + l16;
            const float bbias = (col < 1023) ? bias[col] : 0.f;
#pragma unroll
            for (int m2 = 0; m2 < 4; m2++) {
                const int row0 = (mt0 + m2) * 16 + quad * 4;
#pragma unroll
                for (int r = 0; r < 4; r++) {
                    float sgm = 1.f / (1.f + __expf(-(acc[m2][n2][r] + bbias)));
                    dec[(size_t)(row0 + r) * 1024 + col] = f2b(sgm);
                }
            }
        }
    }
    grid.sync();

    // ======================= P3: pp (full 10-level register walk) =======================
    // 512 units of 16 rows, 2/block in parallel. Per thread: row = tt&15,
    // 64 leaves as 8 groups of 8 consecutive j. Store: lanes vary row fastest
    // -> 64 lanes x 16B = 1KB contiguous per wave store group.
    {
        const int sub = t >> 8, tt = t & 255;
        unsigned short* ds = (unsigned short*)smem + sub * 16384;   // 32KB each
        const int unit = bid * 2 + sub;                              // 0..511
        __syncthreads();
        {   // load 16 rows of dec (32KB) coalesced
            const ushort8v* src = (const ushort8v*)(dec + (size_t)unit * 16 * 1024);
            ushort8v* dst = (ushort8v*)ds;
            for (int g = tt; g < 2048; g += 256) dst[g] = src[g];
        }
        __syncthreads();
        const int r = tt & 15;                     // row within slab
        const unsigned short* dr = ds + r * 1024;
        const size_t rbase = (size_t)unit * 16384 + (size_t)r * 8;
#pragma unroll
        for (int g2 = 0; g2 < 8; g2++) {
            const int jb = (tt >> 4) * 8 + g2 * 128;
            ushort8v o;
#pragma unroll
            for (int e = 0; e < 8; e++) {
                int idx = jb + e;
                float fac[10];
#pragma unroll
                for (int dep = 9; dep >= 0; --dep) {
                    const int half = 1 << dep;
                    const int tb = idx >> dep;
                    const int s  = idx & (half - 1);
                    const int i2 = 2 * s + tb;
                    const int u2 = i2 >> dep;
                    const int rr = i2 & (half - 1);
                    const float dv = b2f(dr[half - 1 + rr]);
                    fac[dep] = u2 ? (1.f - dv) : dv;
                    idx = rr;
                }
                float prod = fac[0];
#pragma unroll
                for (int dep = 1; dep < 10; dep++) prod *= fac[dep];
                o[e] = f2b(prod);
            }
            *(ushort8v*)(A2p + rbase + (size_t)(jb >> 3) * 128) = o;
        }
    }
    grid.sync();

    // ======================= P4: gemm2 (two 4-wave tile groups) =======================
    {
        constexpr int KC = 128;
        const int g4   = wave >> 2;                // tile group 0/1
        const int tid4 = t & 255;
        const int wv4  = wave & 3;
        const int wr2 = wv4 >> 1, wc2 = wv4 & 1;   // 2x2 wave grid, 64x64/wave
        unsigned short* ldsg = (unsigned short*)smem + g4 * 32768;   // 64KB each

        const int bid2 = bid * 2 + g4;             // 0..511
        const int xcd = bid2 & 7;
        const int j   = bid2 >> 3;                 // 0..63
        const int bm  = xcd * 8 + (j & 7);         // 128-row tile idx 0..63
        const int bn  = j >> 3;                    // 0..7

        const int c02 = tid4 >> 4;                 // 0..15
        const int sb  = (tid4 & 15) * 8;
        const unsigned short* gA0w = A2p + ((size_t)(bm * 8 + (c02 >> 2))        * KC + (c02 & 3)) * 128 + sb;
        const unsigned short* gA1w = A2p + ((size_t)(bm * 8 + ((c02 + 16) >> 2)) * KC + (c02 & 3)) * 128 + sb;
        const unsigned short* gB0w = B2p + ((size_t)(bn * 8 + (c02 >> 2))        * KC + (c02 & 3)) * 128 + sb;
        const unsigned short* gB1w = B2p + ((size_t)(bn * 8 + ((c02 + 16) >> 2)) * KC + (c02 & 3)) * 128 + sb;
        const int dA0w = c02 * 128 + sb;
        const int dA1w = (c02 + 16) * 128 + sb;
        const int dB0w = 4096 + c02 * 128 + sb;
        const int dB1w = 4096 + (c02 + 16) * 128 + sb;

        floatx4 acc[4][4] = {};
        constexpr int nks = KC / 4;                // 32 steps

        auto STG2 = [&](int ks, int b) {
            const size_t ko = (size_t)ks * 512;
            unsigned short* lb = ldsg + b * 8192;
            gload16(gA0w + ko, lb + dA0w);
            gload16(gA1w + ko, lb + dA1w);
            gload16(gB0w + ko, lb + dB0w);
            gload16(gB1w + ko, lb + dB1w);
        };

        STG2(0, 0); STG2(1, 1); STG2(2, 2); STG2(3, 3);

        for (int ks = 0; ks < nks - 4; ++ks) {
            G2_STEP(ks, ks & 3, 12, true);
        }
        G2_STEP(nks - 4, (nks - 4) & 3, 12, false);
        G2_STEP(nks - 3, (nks - 3) & 3, 8,  false);
        G2_STEP(nks - 2, (nks - 2) & 3, 4,  false);
        G2_STEP(nks - 1, (nks - 1) & 3, 0,  false);

        const int mt0 = bm * 8 + wr2 * 4;
        const int nt0 = bn * 8 + wc2 * 4;
#pragma unroll
        for (int n2 = 0; n2 < 4; n2++) {
            const int col = (nt0 + n2) * 16 + l16;
#pragma unroll
            for (int m2 = 0; m2 < 4; m2++) {
                const int row0 = (mt0 + m2) * 16 + quad * 4;
#pragma unroll
                for (int r = 0; r < 4; r++) {
                    if (col < 1000) out[(size_t)(row0 + r) * 1000 + col] = acc[m2][n2][r];
                }
            }
        }
    }
}

// ---------- host ----------
extern "C" void kernel_launch(void* const* d_in, const int* in_sizes, int n_in,
                              void* d_out, int out_size, void* d_ws, size_t ws_size,
                              hipStream_t stream) {
    const float* x   = (const float*)d_in[0];   // 8192x2048
    const float* W   = (const float*)d_in[1];   // 2048x1023
    const float* b   = (const float*)d_in[2];   // 1023
    const float* ldd = (const float*)d_in[3];   // 1024x1000
    float* out = (float*)d_out;                 // 8192x1000

    char* ws = (char*)d_ws;
    unsigned short* A2x = (unsigned short*)(ws);              // 33,554,432 B (swizzled x bf16)
    unsigned short* A2p = (unsigned short*)(ws);              // overlay: pp output (A2x dead by then)
    unsigned short* B2w = (unsigned short*)(ws + 33554432);   // 4,194,304 B (swizzled W^T)
    unsigned short* dec = (unsigned short*)(ws + 37748736);   // 16,777,216 B (row-major decisions)
    unsigned short* B2p = (unsigned short*)(ws + 54525952);   // 2,097,152 B (swizzled P^T)

    void* args[] = {(void*)&x, (void*)&W, (void*)&b, (void*)&ldd, (void*)&out,
                    (void*)&A2x, (void*)&B2w, (void*)&dec, (void*)&B2p, (void*)&A2p};
    hipLaunchCooperativeKernel((const void*)mega, dim3(256), dim3(512), args, 0, stream);
}

// Round 9
// 246.520 us; speedup vs baseline: 1.5150x; 1.5150x over previous
//
#include <hip/hip_runtime.h>

// ---------- common helpers ----------
typedef __attribute__((ext_vector_type(8))) unsigned short ushort8v;
typedef __attribute__((ext_vector_type(4))) unsigned short ushort4v;
typedef __attribute__((ext_vector_type(8))) __bf16 bf16x8;
typedef __attribute__((ext_vector_type(4))) float floatx4;

__device__ __forceinline__ unsigned short f2b(float f) {
    unsigned u = __float_as_uint(f);
    unsigned r = u + 0x7fffu + ((u >> 16) & 1u);   // RNE
    return (unsigned short)(r >> 16);
}
__device__ __forceinline__ float b2f(unsigned short h) {
    return __uint_as_float(((unsigned)h) << 16);
}
__device__ __forceinline__ void gload16(const void* g, void* l) {
    __builtin_amdgcn_global_load_lds(
        (const __attribute__((address_space(1))) unsigned int*)g,
        (__attribute__((address_space(3))) unsigned int*)l,
        16, 0, 0);
}

#define VMW(N) asm volatile("s_waitcnt vmcnt(" #N ")" ::: "memory")

// ============================================================================
// R17. R16 post-mortem: mega GPU 270us > 199 (revert fusion); its P3 walk had
// a 16-way LDS conflict (3.95e7, r*1024 rows all bank 0) - my own G4 rule.
// Cooperative path showed 103us non-kernel overhead; interpretation of R15's
// 153us residual (harness overhead vs slow prep/pp/gemm2) still ambiguous.
// This round: back to 4 dispatches (R15 pp/gemm2 verbatim) with ONE change:
// prep's x-pass DELETED - gemm1 stages row-major f32 x directly.
//  - legal: global_load_lds source is per-lane (m173); dest stays linear.
//  - per-lane source pre-swizzle slot^(row&7) -> LDS f32 image where the
//    frag ds_read_b128 hits 2 lanes/bank (free); without it: 16-way.
//  - post-LDS (__bf16) casts are RNE == prep's f2b -> bitwise-identical dec.
//  - schedule/barriers/rotation UNCHANGED; vmcnt 6->10 (5 loads/thr/step).
//  - XCD map bn-per-XCD: B panel 512KB L2-resident; x 67MB L3-resident.
// Removes ~100MB of prep traffic (A2x write+read). gemm1 byte-insensitivity
// proven R9-R14 (384 vs 512MB staged: same time).
// Fragment-swizzled layout (B2w/B2p/A2p): tensor [T16][KC][16][8] bf16;
//   elem (t16, kc, l, e) = Mat[t16*16 + l][kc*8 + e]
// ============================================================================

// ---------- fused prep (x-pass removed) ----------
// blocks [0,2048):    W (2048x1023 f32) -> B2w swizzled bf16 (KC=256)
// blocks [2048,3072): softmax(leaf_dist) -> B2p swizzled bf16 (KC=128), c>=1000 zero
__global__ __launch_bounds__(256) void prep_kernel(const float* __restrict__ W,
                                                   unsigned short* __restrict__ B2w,
                                                   const float* __restrict__ ld_,
                                                   unsigned short* __restrict__ B2p) {
    __shared__ float tile[32 * 33];
    __shared__ float buf[1000];
    __shared__ float red[8];
    const int b = blockIdx.x, t = threadIdx.x;
    if (b < 2048) {                        // ---- transpose+swizzle W, ushort4 stores ----
        const int idx = b;
        const int n0 = (idx & 31) * 32, k0 = (idx >> 5) * 32;
        const int tx = t & 31, ty = t >> 5;
#pragma unroll
        for (int i = 0; i < 4; i++) {
            int k = k0 + ty + i * 8, n = n0 + tx;
            tile[(ty + i * 8) * 33 + tx] = (n < 1023) ? W[(size_t)k * 1023 + n] : 0.f;
        }
        __syncthreads();
        {
            const int tx2 = t & 31, ky = t >> 5;        // ky 0..7 -> 4 consecutive k
            const int n = n0 + tx2;
            const int k = k0 + ky * 4;                  // (k&7) in {0,4}: ushort4-aligned
            ushort4v o;
#pragma unroll
            for (int e = 0; e < 4; e++) o[e] = f2b(tile[(ky * 4 + e) * 33 + tx2]);
            size_t off = ((size_t)((n >> 4) * 256 + (k >> 3)) * 16 + (n & 15)) * 8 + (k & 7);
            *(ushort4v*)(B2w + off) = o;
        }
    } else {                               // ---- softmax -> B2p swizzled (+zero pad) ----
        const int l0 = b - 2048;
        const float* r = ld_ + (size_t)l0 * 1000;
        float mx = -3.4e38f;
        for (int i = t; i < 1000; i += 256) { float v = r[i]; buf[i] = v; mx = fmaxf(mx, v); }
#pragma unroll
        for (int o = 32; o > 0; o >>= 1) mx = fmaxf(mx, __shfl_down(mx, o));
        if ((t & 63) == 0) red[t >> 6] = mx;
        __syncthreads();
        mx = fmaxf(fmaxf(red[0], red[1]), fmaxf(red[2], red[3]));
        float s = 0.f;
        for (int i = t; i < 1000; i += 256) { float e = __expf(buf[i] - mx); buf[i] = e; s += e; }
#pragma unroll
        for (int o = 32; o > 0; o >>= 1) s += __shfl_down(s, o);
        if ((t & 63) == 0) red[4 + (t >> 6)] = s;
        __syncthreads();
        float inv = 1.f / (red[4] + red[5] + red[6] + red[7]);
        for (int i = t; i < 1024; i += 256) {
            float pv = (i < 1000) ? buf[i] * inv : 0.f;
            size_t off = ((size_t)((i >> 4) * 128 + (l0 >> 3)) * 16 + (i & 15)) * 8 + (l0 & 7);
            B2p[off] = f2b(pv);
        }
    }
}

// ---------- pp: R15 verbatim (direct levels 0-5, iterative 6-9, vec stores) ----------
__global__ __launch_bounds__(256) void pp_kernel(const unsigned short* __restrict__ dec,
                                                 unsigned short* __restrict__ A2p) {
    __shared__ unsigned short dsh[8 * 1024];
    __shared__ float pa[8 * 1024];
    __shared__ float pb[8 * 1024];
    const int t = threadIdx.x;
    const int r0 = blockIdx.x * 8;
    {
        const ushort8v* src = (const ushort8v*)(dec + (size_t)r0 * 1024);
        ushort8v* dst = (ushort8v*)dsh;
        for (int g = t; g < 1024; g += 256) dst[g] = src[g];
    }
    __syncthreads();
    {
        const int r  = t >> 5;             // 0..7
        const int jb = (t & 31) * 2;
        const unsigned short* dr = &dsh[r * 1024];
#pragma unroll
        for (int e = 0; e < 2; e++) {
            int idx = jb + e;
            float fac[6];
#pragma unroll
            for (int dep = 5; dep >= 0; --dep) {
                const int half = 1 << dep;
                const int tt = idx >> dep;
                const int s  = idx & (half - 1);
                const int i2 = 2 * s + tt;
                const int u  = i2 >> dep;
                const int rr = i2 & (half - 1);
                const float dv = b2f(dr[half - 1 + rr]);
                fac[dep] = u ? (1.f - dv) : dv;
                idx = rr;
            }
            float prod = fac[0];
#pragma unroll
            for (int dep = 1; dep < 6; dep++) prod *= fac[dep];
            pa[r * 1024 + jb + e] = prod;
        }
    }
    __syncthreads();
    float* cur = pa; float* nxt = pb;
    for (int dep = 6; dep < 10; dep++) {
        const int half = 1 << dep;
        const int len  = half << 1;
        const int total = len << 3;        // 8 rows
        for (int idx = t; idx < total; idx += 256) {
            const int r = idx >> (dep + 1);
            const int j = idx & (len - 1);
            int tt = j >> dep;
            int s  = j & (half - 1);
            int i2 = 2 * s + tt;
            int u  = i2 >> dep;
            int rr = i2 & (half - 1);
            float dv = b2f(dsh[r * 1024 + half - 1 + rr]);
            nxt[r * 1024 + j] = cur[r * 1024 + rr] * (u ? (1.f - dv) : dv);
        }
        __syncthreads();
        float* tmp = cur; cur = nxt; nxt = tmp;
    }
    {
        const int r  = t >> 5;             // 0..7
        const int jb = (t & 31) * 32;
        const int rrow = r0 + r;
        const float* cr = &cur[r * 1024];
        const size_t rbase = (size_t)(rrow >> 4) * 128 * 128 + (size_t)(rrow & 15) * 8;
#pragma unroll
        for (int g = 0; g < 8; g++) {
            const int j = jb + g * 4;
            ushort4v o;
            o[0] = f2b(cr[j]); o[1] = f2b(cr[j + 1]);
            o[2] = f2b(cr[j + 2]); o[3] = f2b(cr[j + 3]);
            size_t off = rbase + (size_t)(j >> 3) * 128 + (j & 7);
            *(ushort4v*)(A2p + off) = o;
        }
    }
}

// ---------- gemm1: 256x128 tile, 8 waves, 3 rotating buffers, f32-x staging ----------
// A buffer (32KB f32): [slab 0..15][row 0..15][8 x 16B kparts], kpart slot holds
// global kpart (slot ^ (row&7)) -> frag ds_read_b128 is 2 lanes/bank (free).
// B buffer (8KB bf16): chunk layout as before. 3 bufs = 120KB -> 1 block/CU.
// Stage = 5 gload16/thread (A 4, B 1); steady vmcnt(10), tail 5/0.
// Schedule identical to R15's proven loop; conversion RNE == f2b (bit-identical).
#define M1_STEP(ks_, CUR_, STG_, VM_, DOSTAGE_)                                       \
    {                                                                                 \
        if (DOSTAGE_) STAGE((ks_) + 2, (STG_));                                       \
        VMW(VM_);                                                                     \
        __builtin_amdgcn_s_barrier();                                                 \
        const float* lA = ldsA[(CUR_)];                                               \
        const unsigned short* lB = ldsB[(CUR_)];                                      \
        float4 a0[4], a1[4]; bf16x8 bv[4];                                            \
        _Pragma("unroll")                                                             \
        for (int m2 = 0; m2 < 4; m2++) {                                              \
            const int sb = (wr * 4 + m2) * 512 + l16 * 32;                            \
            a0[m2] = *(const float4*)&lA[sb + (((quad * 2) ^ (l16 & 7)) * 4)];        \
            a1[m2] = *(const float4*)&lA[sb + (((quad * 2 + 1) ^ (l16 & 7)) * 4)];    \
        }                                                                             \
        _Pragma("unroll")                                                             \
        for (int n2 = 0; n2 < 4; n2++)                                                \
            bv[n2] = __builtin_bit_cast(bf16x8,                                       \
                *(const ushort8v*)&lB[((wc * 4 + n2) * 4 + quad) * 128 + l16 * 8]);   \
        asm volatile("s_waitcnt lgkmcnt(0)" ::: "memory");                            \
        __builtin_amdgcn_sched_barrier(0);                                            \
        bf16x8 af[4];                                                                 \
        _Pragma("unroll")                                                             \
        for (int m2 = 0; m2 < 4; m2++) {                                              \
            af[m2][0] = (__bf16)a0[m2].x; af[m2][1] = (__bf16)a0[m2].y;               \
            af[m2][2] = (__bf16)a0[m2].z; af[m2][3] = (__bf16)a0[m2].w;               \
            af[m2][4] = (__bf16)a1[m2].x; af[m2][5] = (__bf16)a1[m2].y;               \
            af[m2][6] = (__bf16)a1[m2].z; af[m2][7] = (__bf16)a1[m2].w;               \
        }                                                                             \
        __builtin_amdgcn_s_setprio(1);                                                \
        _Pragma("unroll")                                                             \
        for (int m2 = 0; m2 < 4; m2++)                                                \
            _Pragma("unroll")                                                         \
            for (int n2 = 0; n2 < 4; n2++)                                            \
                acc[m2][n2] = __builtin_amdgcn_mfma_f32_16x16x32_bf16(                \
                    af[m2], bv[n2], acc[m2][n2], 0, 0, 0);                            \
        __builtin_amdgcn_s_setprio(0);                                                \
        __builtin_amdgcn_s_barrier();                                                 \
    }

__global__ __launch_bounds__(512, 1) void gemm_m1(const float* __restrict__ x,
                                                  const unsigned short* __restrict__ B2,
                                                  const float* __restrict__ bias,
                                                  unsigned short* __restrict__ obf) {
    constexpr int KC = 256;                    // B kc-chunks over K=2048
    __shared__ float          ldsA[3][8192];   // 3 x 32KB (f32 A)
    __shared__ unsigned short ldsB[3][4096];   // 3 x 8KB  (bf16 B)

    const int t    = threadIdx.x;              // 0..511
    const int lane = t & 63;
    const int wave = t >> 6;                   // 0..7
    const int quad = lane >> 4, l16 = lane & 15;
    const int wr = wave >> 1, wc = wave & 1;   // 4M x 2N wave grid, 64x64/wave

    const int bid = blockIdx.x;                // 256 blocks
    const int bn  = bid & 7;                   // bn == XCD: B panel (512KB) L2-resident
    const int bm  = bid >> 3;                  // 0..31 (256-row tiles); x via L3

    // A stage: instr i covers li = i*512+t -> (slab,row,slot); per-lane source
    // pre-swizzled so linear LDS dest == swizzled image.
    const float* srcA[4];
#pragma unroll
    for (int i = 0; i < 4; i++) {
        const int li = i * 512 + t;
        const int slab = li >> 7, row = (li >> 3) & 15, slot = li & 7;
        srcA[i] = x + (size_t)(bm * 256 + slab * 16 + row) * 2048 + (slot ^ (row & 7)) * 4;
    }
    // B stage (linear, layout unchanged)
    const int cB  = t >> 4;                    // 0..31
    const int sub = (t & 15) * 8;
    const unsigned short* gB0 = B2 + ((size_t)(bn * 8 + (cB >> 2)) * KC + (cB & 3)) * 128 + sub;
    const int dB0 = cB * 128 + sub;

    floatx4 acc[4][4] = {};
    constexpr int nks = 64;                    // BK=32 f32 per step

    auto STAGE = [&](int ks, int b) {
#pragma unroll
        for (int i = 0; i < 4; i++)
            gload16(srcA[i] + ks * 32, &ldsA[b][(i * 512 + t) * 4]);
        gload16(gB0 + (size_t)ks * 512, &ldsB[b][dB0]);
    };

    STAGE(0, 0); STAGE(1, 1);
    int c0 = 0, c1 = 1, c2 = 2;
    for (int ks = 0; ks < nks - 2; ++ks) {
        M1_STEP(ks, c0, c2, 10, true);
        int tmp = c0; c0 = c1; c1 = c2; c2 = tmp;
    }
    M1_STEP(nks - 2, c0, c2, 5, false);
    { int tmp = c0; c0 = c1; c1 = c2; c2 = tmp; }
    M1_STEP(nks - 1, c0, c2, 0, false);

    // ---- epilogue: sigmoid(acc + bias[col]) -> bf16, ldo=1024 ----
    const int mt0 = bm * 16 + wr * 4;
    const int nt0 = bn * 8  + wc * 4;
#pragma unroll
    for (int n2 = 0; n2 < 4; n2++) {
        const int col = (nt0 + n2) * 16 + l16;
        const float bbias = (col < 1023) ? bias[col] : 0.f;
#pragma unroll
        for (int m2 = 0; m2 < 4; m2++) {
            const int row0 = (mt0 + m2) * 16 + quad * 4;
#pragma unroll
            for (int r = 0; r < 4; r++) {
                float sgm = 1.f / (1.f + __expf(-(acc[m2][n2][r] + bbias)));
                obf[(size_t)(row0 + r) * 1024 + col] = f2b(sgm);
            }
        }
    }
}

// ---------- gemm2: 128x128, 4 waves, 4 buffers, counted vmcnt (R11/R15-proven) ----------
#define P4_STEP(ks_, b_, VM_, DOSTAGE_)                                             \
    {                                                                               \
        VMW(VM_);                                                                   \
        __builtin_amdgcn_s_barrier();                                               \
        __builtin_amdgcn_sched_barrier(0);                                          \
        const unsigned short* lA = &lds[(b_)][0];                                   \
        const unsigned short* lB = &lds[(b_)][4096];                                \
        bf16x8 af[4], bv[4];                                                        \
        _Pragma("unroll")                                                           \
        for (int m2 = 0; m2 < 4; m2++)                                              \
            af[m2] = __builtin_bit_cast(bf16x8,                                     \
                *(const ushort8v*)&lA[((wr * 4 + m2) * 4 + quad) * 128 + l16 * 8]); \
        _Pragma("unroll")                                                           \
        for (int n2 = 0; n2 < 4; n2++)                                              \
            bv[n2] = __builtin_bit_cast(bf16x8,                                     \
                *(const ushort8v*)&lB[((wc * 4 + n2) * 4 + quad) * 128 + l16 * 8]); \
        asm volatile("s_waitcnt lgkmcnt(0)" ::: "memory");                          \
        __builtin_amdgcn_sched_barrier(0);                                          \
        __builtin_amdgcn_s_barrier();                                               \
        __builtin_amdgcn_sched_barrier(0);                                          \
        if (DOSTAGE_) STAGE((ks_) + 4, (b_));                                       \
        __builtin_amdgcn_s_setprio(1);                                              \
        _Pragma("unroll")                                                           \
        for (int m2 = 0; m2 < 4; m2++)                                              \
            _Pragma("unroll")                                                       \
            for (int n2 = 0; n2 < 4; n2++)                                          \
                acc[m2][n2] = __builtin_amdgcn_mfma_f32_16x16x32_bf16(              \
                    af[m2], bv[n2], acc[m2][n2], 0, 0, 0);                          \
        __builtin_amdgcn_s_setprio(0);                                              \
    }

template <int KC>
__global__ __launch_bounds__(256, 2) void gemm_p4(const unsigned short* __restrict__ A2,
                                                  const unsigned short* __restrict__ B2,
                                                  float* __restrict__ of32, int ldo) {
    __shared__ unsigned short lds[4][8192];

    const int tid  = threadIdx.x;
    const int lane = tid & 63;
    const int wave = tid >> 6;
    const int quad = lane >> 4, l16 = lane & 15;
    const int wr = wave >> 1, wc = wave & 1;

    const int bid = blockIdx.x;
    const int xcd = bid & 7;
    const int j   = bid >> 3;
    const int bm  = xcd * 8 + (j & 7);
    const int bn  = j >> 3;

    const int c0  = tid >> 4;
    const int sub = (tid & 15) * 8;
    const unsigned short* gA0 = A2 + ((size_t)(bm * 8 + (c0 >> 2))        * KC + (c0 & 3)) * 128 + sub;
    const unsigned short* gA1 = A2 + ((size_t)(bm * 8 + ((c0 + 16) >> 2)) * KC + (c0 & 3)) * 128 + sub;
    const unsigned short* gB0 = B2 + ((size_t)(bn * 8 + (c0 >> 2))        * KC + (c0 & 3)) * 128 + sub;
    const unsigned short* gB1 = B2 + ((size_t)(bn * 8 + ((c0 + 16) >> 2)) * KC + (c0 & 3)) * 128 + sub;
    const int dA0 = c0 * 128 + sub;
    const int dA1 = (c0 + 16) * 128 + sub;
    const int dB0 = 4096 + c0 * 128 + sub;
    const int dB1 = 4096 + (c0 + 16) * 128 + sub;

    floatx4 acc[4][4] = {};
    constexpr int nks = KC / 4;

    auto STAGE = [&](int ks, int b) {
        const size_t ko = (size_t)ks * 512;
        gload16(gA0 + ko, &lds[b][dA0]);
        gload16(gA1 + ko, &lds[b][dA1]);
        gload16(gB0 + ko, &lds[b][dB0]);
        gload16(gB1 + ko, &lds[b][dB1]);
    };

    STAGE(0, 0); STAGE(1, 1); STAGE(2, 2); STAGE(3, 3);

    for (int ks = 0; ks < nks - 4; ++ks) {
        P4_STEP(ks, ks & 3, 12, true);
    }
    P4_STEP(nks - 4, (nks - 4) & 3, 12, false);
    P4_STEP(nks - 3, (nks - 3) & 3, 8,  false);
    P4_STEP(nks - 2, (nks - 2) & 3, 4,  false);
    P4_STEP(nks - 1, (nks - 1) & 3, 0,  false);

    const int mt0 = bm * 8 + wr * 4;
    const int nt0 = bn * 8 + wc * 4;
#pragma unroll
    for (int n2 = 0; n2 < 4; n2++) {
        const int col = (nt0 + n2) * 16 + l16;
#pragma unroll
        for (int m2 = 0; m2 < 4; m2++) {
            const int row0 = (mt0 + m2) * 16 + quad * 4;
#pragma unroll
            for (int r = 0; r < 4; r++) {
                if (col < 1000) of32[(size_t)(row0 + r) * ldo + col] = acc[m2][n2][r];
            }
        }
    }
}

// ---------- host ----------
extern "C" void kernel_launch(void* const* d_in, const int* in_sizes, int n_in,
                              void* d_out, int out_size, void* d_ws, size_t ws_size,
                              hipStream_t stream) {
    const float* x   = (const float*)d_in[0];   // 8192x2048
    const float* W   = (const float*)d_in[1];   // 2048x1023
    const float* b   = (const float*)d_in[2];   // 1023
    const float* ldd = (const float*)d_in[3];   // 1024x1000
    float* out = (float*)d_out;                 // 8192x1000

    char* ws = (char*)d_ws;
    unsigned short* A2p = (unsigned short*)(ws);              // 16,777,216 B (pp output, swizzled)
    unsigned short* B2w = (unsigned short*)(ws + 33554432);   //  4,194,304 B (swizzled W^T)
    unsigned short* dec = (unsigned short*)(ws + 37748736);   // 16,777,216 B (row-major decisions)
    unsigned short* B2p = (unsigned short*)(ws + 54525952);   //  2,097,152 B (swizzled P^T)

    // prep: W-transpose-swizzle | softmax->swizzle (x-pass removed)
    prep_kernel<<<3072, 256, 0, stream>>>(W, B2w, ldd, B2p);
    // decisions = sigmoid(x@W + b): stages f32 x directly (pre-swizzled source)
    gemm_m1<<<256, 512, 0, stream>>>(x, B2w, b, dec);
    // pp (reference-literal order), 8 rows/block, writes swizzled A2p
    pp_kernel<<<1024, 256, 0, stream>>>(dec, A2p);
    // out = pp @ P
    gemm_p4<128><<<512, 256, 0, stream>>>(A2p, B2p, out, 1000);
}

// Round 11
// 200.394 us; speedup vs baseline: 1.8637x; 1.2302x over previous
//
#include <hip/hip_runtime.h>

// ---------- common helpers ----------
typedef __attribute__((ext_vector_type(8))) unsigned short ushort8v;
typedef __attribute__((ext_vector_type(4))) unsigned short ushort4v;
typedef __attribute__((ext_vector_type(8))) __bf16 bf16x8;
typedef __attribute__((ext_vector_type(4))) float floatx4;

__device__ __forceinline__ unsigned short f2b(float f) {
    unsigned u = __float_as_uint(f);
    unsigned r = u + 0x7fffu + ((u >> 16) & 1u);   // RNE
    return (unsigned short)(r >> 16);
}
__device__ __forceinline__ float b2f(unsigned short h) {
    return __uint_as_float(((unsigned)h) << 16);
}
__device__ __forceinline__ void gload16(const void* g, void* l) {
    __builtin_amdgcn_global_load_lds(
        (const __attribute__((address_space(1))) unsigned int*)g,
        (__attribute__((address_space(3))) unsigned int*)l,
        16, 0, 0);
}

#define VMW(N) asm volatile("s_waitcnt vmcnt(" #N ")" ::: "memory")

// ============================================================================
// R19 == R18 with the race FIXED. R18's NaN root cause: M8_STEP read LDS
// immediately after the per-wave VMW(6) without a barrier. vmcnt only proves
// THIS wave's loads landed; fragments are written by OTHER waves' gload_lds.
// R15's proven order is VMW -> s_barrier -> ds_read (barrier upgrades the
// per-wave guarantee to block-wide). Fix: one s_barrier at step top between
// VMW and phase 0's reads (9 barriers/step). All other R18 reasoning stands:
// 4-phase interleave at 1 blk/CU per m201 (19.9 B/cyc/CU vs our 13.8),
// 256x128, BK=64, 8 waves, 3 rotating 48KB buffers, steady vmcnt(6),
// tail 6/0, K order == two R15 BK=32 steps -> bitwise-identical output.
// prep/pp/gemm2 R15 VERBATIM.
// Fragment-swizzled layout: tensor [T16][KC][16][8] bf16;
//   elem (t16, kc, l, e) = Mat[t16*16 + l][kc*8 + e]
// ============================================================================

// ---------- fused prep (R15 verbatim) ----------
__global__ __launch_bounds__(256) void prep_kernel(const float* __restrict__ x,
                                                   unsigned short* __restrict__ A2x,
                                                   const float* __restrict__ W,
                                                   unsigned short* __restrict__ B2w,
                                                   const float* __restrict__ ld_,
                                                   unsigned short* __restrict__ B2p) {
    __shared__ float tile[32 * 33];
    __shared__ float buf[1000];
    __shared__ float red[8];
    const int b = blockIdx.x, t = threadIdx.x;
    if (b < 2048) {                        // ---- cvt+swizzle x ----
        const int mt = b >> 2, kq = (b & 3) * 64;
        const int l16 = t >> 4;
        const int sg  = t & 15;
        const float* xr = x + (size_t)(mt * 16 + l16) * 2048 + (size_t)(kq + sg * 4) * 8;
#pragma unroll
        for (int c = 0; c < 4; c++) {
            float4 v0 = *(const float4*)(xr + c * 8);
            float4 v1 = *(const float4*)(xr + c * 8 + 4);
            ushort8v o;
            o[0] = f2b(v0.x); o[1] = f2b(v0.y); o[2] = f2b(v0.z); o[3] = f2b(v0.w);
            o[4] = f2b(v1.x); o[5] = f2b(v1.y); o[6] = f2b(v1.z); o[7] = f2b(v1.w);
            const int kc = kq + sg * 4 + c;
            *(ushort8v*)(A2x + ((size_t)(mt * 256 + kc) * 16 + l16) * 8) = o;
        }
    } else if (b < 4096) {                 // ---- transpose+swizzle W, ushort4 stores ----
        const int idx = b - 2048;
        const int n0 = (idx & 31) * 32, k0 = (idx >> 5) * 32;
        const int tx = t & 31, ty = t >> 5;
#pragma unroll
        for (int i = 0; i < 4; i++) {
            int k = k0 + ty + i * 8, n = n0 + tx;
            tile[(ty + i * 8) * 33 + tx] = (n < 1023) ? W[(size_t)k * 1023 + n] : 0.f;
        }
        __syncthreads();
        {
            const int tx2 = t & 31, ky = t >> 5;
            const int n = n0 + tx2;
            const int k = k0 + ky * 4;
            ushort4v o;
#pragma unroll
            for (int e = 0; e < 4; e++) o[e] = f2b(tile[(ky * 4 + e) * 33 + tx2]);
            size_t off = ((size_t)((n >> 4) * 256 + (k >> 3)) * 16 + (n & 15)) * 8 + (k & 7);
            *(ushort4v*)(B2w + off) = o;
        }
    } else {                               // ---- softmax -> B2p swizzled ----
        const int l0 = b - 4096;
        const float* r = ld_ + (size_t)l0 * 1000;
        float mx = -3.4e38f;
        for (int i = t; i < 1000; i += 256) { float v = r[i]; buf[i] = v; mx = fmaxf(mx, v); }
#pragma unroll
        for (int o = 32; o > 0; o >>= 1) mx = fmaxf(mx, __shfl_down(mx, o));
        if ((t & 63) == 0) red[t >> 6] = mx;
        __syncthreads();
        mx = fmaxf(fmaxf(red[0], red[1]), fmaxf(red[2], red[3]));
        float s = 0.f;
        for (int i = t; i < 1000; i += 256) { float e = __expf(buf[i] - mx); buf[i] = e; s += e; }
#pragma unroll
        for (int o = 32; o > 0; o >>= 1) s += __shfl_down(s, o);
        if ((t & 63) == 0) red[4 + (t >> 6)] = s;
        __syncthreads();
        float inv = 1.f / (red[4] + red[5] + red[6] + red[7]);
        for (int i = t; i < 1024; i += 256) {
            float pv = (i < 1000) ? buf[i] * inv : 0.f;
            size_t off = ((size_t)((i >> 4) * 128 + (l0 >> 3)) * 16 + (i & 15)) * 8 + (l0 & 7);
            B2p[off] = f2b(pv);
        }
    }
}

// ---------- pp: R15 verbatim ----------
__global__ __launch_bounds__(256) void pp_kernel(const unsigned short* __restrict__ dec,
                                                 unsigned short* __restrict__ A2p) {
    __shared__ unsigned short dsh[8 * 1024];
    __shared__ float pa[8 * 1024];
    __shared__ float pb[8 * 1024];
    const int t = threadIdx.x;
    const int r0 = blockIdx.x * 8;
    {
        const ushort8v* src = (const ushort8v*)(dec + (size_t)r0 * 1024);
        ushort8v* dst = (ushort8v*)dsh;
        for (int g = t; g < 1024; g += 256) dst[g] = src[g];
    }
    __syncthreads();
    {
        const int r  = t >> 5;
        const int jb = (t & 31) * 2;
        const unsigned short* dr = &dsh[r * 1024];
#pragma unroll
        for (int e = 0; e < 2; e++) {
            int idx = jb + e;
            float fac[6];
#pragma unroll
            for (int dep = 5; dep >= 0; --dep) {
                const int half = 1 << dep;
                const int tt = idx >> dep;
                const int s  = idx & (half - 1);
                const int i2 = 2 * s + tt;
                const int u  = i2 >> dep;
                const int rr = i2 & (half - 1);
                const float dv = b2f(dr[half - 1 + rr]);
                fac[dep] = u ? (1.f - dv) : dv;
                idx = rr;
            }
            float prod = fac[0];
#pragma unroll
            for (int dep = 1; dep < 6; dep++) prod *= fac[dep];
            pa[r * 1024 + jb + e] = prod;
        }
    }
    __syncthreads();
    float* cur = pa; float* nxt = pb;
    for (int dep = 6; dep < 10; dep++) {
        const int half = 1 << dep;
        const int len  = half << 1;
        const int total = len << 3;
        for (int idx = t; idx < total; idx += 256) {
            const int r = idx >> (dep + 1);
            const int j = idx & (len - 1);
            int tt = j >> dep;
            int s  = j & (half - 1);
            int i2 = 2 * s + tt;
            int u  = i2 >> dep;
            int rr = i2 & (half - 1);
            float dv = b2f(dsh[r * 1024 + half - 1 + rr]);
            nxt[r * 1024 + j] = cur[r * 1024 + rr] * (u ? (1.f - dv) : dv);
        }
        __syncthreads();
        float* tmp = cur; cur = nxt; nxt = tmp;
    }
    {
        const int r  = t >> 5;
        const int jb = (t & 31) * 32;
        const int rrow = r0 + r;
        const float* cr = &cur[r * 1024];
        const size_t rbase = (size_t)(rrow >> 4) * 128 * 128 + (size_t)(rrow & 15) * 8;
#pragma unroll
        for (int g = 0; g < 8; g++) {
            const int j = jb + g * 4;
            ushort4v o;
            o[0] = f2b(cr[j]); o[1] = f2b(cr[j + 1]);
            o[2] = f2b(cr[j + 2]); o[3] = f2b(cr[j + 3]);
            size_t off = rbase + (size_t)(j >> 3) * 128 + (j & 7);
            *(ushort4v*)(A2p + off) = o;
        }
    }
}

// ---------- gemm1: 256x128, BK=64, 8 waves, 3 rotating bufs, 4-phase interleave ----------
// Buffer (48KB ushorts[24576]): A = 16 slabs x 8 kc-chunks = 128 chunks (32KB)
// at [0..16384), B = 8 slabs x 8 chunks = 64 chunks (16KB) at [16384..24576).
// Stage = 6 gload16/thread/step (A:4, B:2), issued 2/2/1/1 across phases.
// Step top: VMW(6) -> s_barrier (per-wave vmcnt upgraded to block-wide; R18's
// missing barrier was the NaN race) -> phases. Tail 6/0.
#define RD_A(m2_, kk_) __builtin_bit_cast(bf16x8, \
    *(const ushort8v*)&lA[((wr * 4 + (m2_)) * 8 + (kk_) * 4 + quad) * 128 + l16 * 8])
#define RD_B(n2_, kk_) __builtin_bit_cast(bf16x8, \
    *(const ushort8v*)&lB[((wc * 4 + (n2_)) * 8 + (kk_) * 4 + quad) * 128 + l16 * 8])
#define MM(AV_, m2_, n2_, BV_) acc[m2_][n2_] = \
    __builtin_amdgcn_mfma_f32_16x16x32_bf16(AV_, BV_, acc[m2_][n2_], 0, 0, 0);
#define STG_A(ks_, b_, i_) gload16(gA[i_] + (size_t)(ks_) * 1024, &lds[b_][(i_) * 4096 + dA]);
#define STG_B(ks_, b_, i_) gload16(gB[i_] + (size_t)(ks_) * 1024, &lds[b_][(i_) * 4096 + dB]);

#define PH_TAIL                                         \
    __builtin_amdgcn_s_barrier();                       \
    asm volatile("s_waitcnt lgkmcnt(0)" ::: "memory");  \
    __builtin_amdgcn_sched_barrier(0);                  \
    __builtin_amdgcn_s_setprio(1);

#define PH_END                                          \
    __builtin_amdgcn_s_setprio(0);                      \
    __builtin_amdgcn_s_barrier();

#define M8_STEP(ks_, CUR_, STG_, VM_, DOSTAGE_)                                   \
    {                                                                             \
        VMW(VM_);                                                                 \
        __builtin_amdgcn_s_barrier();   /* block-wide data-ready (R18 fix) */     \
        const unsigned short* lA = &lds[(CUR_)][0];                               \
        const unsigned short* lB = &lds[(CUR_)][16384];                           \
        bf16x8 aE, aO, b0, b1, b2, b3;                                            \
        /* phase 0: kk=0, m2=0,1 */                                               \
        aE = RD_A(0, 0); aO = RD_A(1, 0);                                         \
        b0 = RD_B(0, 0); b1 = RD_B(1, 0); b2 = RD_B(2, 0); b3 = RD_B(3, 0);       \
        if (DOSTAGE_) { STG_A((ks_) + 2, STG_, 0); STG_A((ks_) + 2, STG_, 1); }   \
        PH_TAIL                                                                   \
        MM(aE, 0, 0, b0) MM(aE, 0, 1, b1) MM(aE, 0, 2, b2) MM(aE, 0, 3, b3)       \
        MM(aO, 1, 0, b0) MM(aO, 1, 1, b1) MM(aO, 1, 2, b2) MM(aO, 1, 3, b3)       \
        PH_END                                                                    \
        /* phase 1: kk=0, m2=2,3 */                                               \
        aE = RD_A(2, 0); aO = RD_A(3, 0);                                         \
        if (DOSTAGE_) { STG_A((ks_) + 2, STG_, 2); STG_A((ks_) + 2, STG_, 3); }   \
        PH_TAIL                                                                   \
        MM(aE, 2, 0, b0) MM(aE, 2, 1, b1) MM(aE, 2, 2, b2) MM(aE, 2, 3, b3)       \
        MM(aO, 3, 0, b0) MM(aO, 3, 1, b1) MM(aO, 3, 2, b2) MM(aO, 3, 3, b3)       \
        PH_END                                                                    \
        /* phase 2: kk=1, m2=0,1 */                                               \
        aE = RD_A(0, 1); aO = RD_A(1, 1);                                         \
        b0 = RD_B(0, 1); b1 = RD_B(1, 1); b2 = RD_B(2, 1); b3 = RD_B(3, 1);       \
        if (DOSTAGE_) { STG_B((ks_) + 2, STG_, 0); }                              \
        PH_TAIL                                                                   \
        MM(aE, 0, 0, b0) MM(aE, 0, 1, b1) MM(aE, 0, 2, b2) MM(aE, 0, 3, b3)       \
        MM(aO, 1, 0, b0) MM(aO, 1, 1, b1) MM(aO, 1, 2, b2) MM(aO, 1, 3, b3)       \
        PH_END                                                                    \
        /* phase 3: kk=1, m2=2,3 */                                               \
        aE = RD_A(2, 1); aO = RD_A(3, 1);                                         \
        if (DOSTAGE_) { STG_B((ks_) + 2, STG_, 1); }                              \
        PH_TAIL                                                                   \
        MM(aE, 2, 0, b0) MM(aE, 2, 1, b1) MM(aE, 2, 2, b2) MM(aE, 2, 3, b3)       \
        MM(aO, 3, 0, b0) MM(aO, 3, 1, b1) MM(aO, 3, 2, b2) MM(aO, 3, 3, b3)       \
        PH_END                                                                    \
    }

__global__ __launch_bounds__(512, 1) void gemm_m1(const unsigned short* __restrict__ A2,
                                                  const unsigned short* __restrict__ B2,
                                                  const float* __restrict__ bias,
                                                  unsigned short* __restrict__ obf) {
    constexpr int KC = 256;                    // total kc-chunks over K=2048
    __shared__ unsigned short lds[3][24576];   // 3 x 48KB = 144KB -> 1 block/CU

    const int t    = threadIdx.x;              // 0..511
    const int lane = t & 63;
    const int wave = t >> 6;                   // 0..7
    const int quad = lane >> 4, l16 = lane & 15;
    const int wr = wave >> 1, wc = wave & 1;   // 4M x 2N wave grid, 64x64/wave

    const int bid = blockIdx.x;                // 256 blocks
    const int xcd = bid & 7;
    const int j   = bid >> 3;                  // 0..31
    const int bm  = xcd * 4 + (j & 3);         // 0..31 (256-row tiles)
    const int bn  = j >> 2;                    // 0..7  (128-col tiles)

    // stage map: A issue i covers chunks c = i*32 + (t>>4); slab=c>>3, kcq=c&7.
    const int cT  = t >> 4;                    // 0..31
    const int sub = (t & 15) * 8;
    const unsigned short* gA[4];
    const unsigned short* gB[2];
#pragma unroll
    for (int i = 0; i < 4; i++) {
        const int c = i * 32 + cT;
        gA[i] = A2 + ((size_t)(bm * 16 + (c >> 3)) * KC + (c & 7)) * 128 + sub;
    }
#pragma unroll
    for (int i = 0; i < 2; i++) {
        const int c = i * 32 + cT;
        gB[i] = B2 + ((size_t)(bn * 8 + (c >> 3)) * KC + (c & 7)) * 128 + sub;
    }
    const int dA = cT * 128 + sub;             // + i*4096 (lane-linear: base + tid*16B)
    const int dB = 16384 + cT * 128 + sub;

    floatx4 acc[4][4] = {};
    constexpr int nks = 32;                    // BK=64 -> 8 kc-chunks/step

    // prologue: stage steps 0,1 (6 issues each, same order as steady state)
    STG_A(0, 0, 0) STG_A(0, 0, 1) STG_A(0, 0, 2) STG_A(0, 0, 3) STG_B(0, 0, 0) STG_B(0, 0, 1)
    STG_A(1, 1, 0) STG_A(1, 1, 1) STG_A(1, 1, 2) STG_A(1, 1, 3) STG_B(1, 1, 0) STG_B(1, 1, 1)

    int c0 = 0, c1 = 1, c2 = 2;
    for (int ks = 0; ks < nks - 2; ++ks) {
        M8_STEP(ks, c0, c2, 6, true);
        int tmp = c0; c0 = c1; c1 = c2; c2 = tmp;
    }
    M8_STEP(nks - 2, c0, c2, 6, false);
    { int tmp = c0; c0 = c1; c1 = c2; c2 = tmp; }
    M8_STEP(nks - 1, c0, c2, 0, false);

    // ---- epilogue: sigmoid(acc + bias[col]) -> bf16, ldo=1024 ----
    const int mt0 = bm * 16 + wr * 4;
    const int nt0 = bn * 8  + wc * 4;
#pragma unroll
    for (int n2 = 0; n2 < 4; n2++) {
        const int col = (nt0 + n2) * 16 + l16;
        const float bbias = (col < 1023) ? bias[col] : 0.f;
#pragma unroll
        for (int m2 = 0; m2 < 4; m2++) {
            const int row0 = (mt0 + m2) * 16 + quad * 4;
#pragma unroll
            for (int r = 0; r < 4; r++) {
                float sgm = 1.f / (1.f + __expf(-(acc[m2][n2][r] + bbias)));
                obf[(size_t)(row0 + r) * 1024 + col] = f2b(sgm);
            }
        }
    }
}

// ---------- gemm2: R15 verbatim (128x128, 4 waves, 4 buffers, counted vmcnt) ----------
#define P4_STEP(ks_, b_, VM_, DOSTAGE_)                                             \
    {                                                                               \
        VMW(VM_);                                                                   \
        __builtin_amdgcn_s_barrier();                                               \
        __builtin_amdgcn_sched_barrier(0);                                          \
        const unsigned short* lA = &lds[(b_)][0];                                   \
        const unsigned short* lB = &lds[(b_)][4096];                                \
        bf16x8 af[4], bv[4];                                                        \
        _Pragma("unroll")                                                           \
        for (int m2 = 0; m2 < 4; m2++)                                              \
            af[m2] = __builtin_bit_cast(bf16x8,                                     \
                *(const ushort8v*)&lA[((wr * 4 + m2) * 4 + quad) * 128 + l16 * 8]); \
        _Pragma("unroll")                                                           \
        for (int n2 = 0; n2 < 4; n2++)                                              \
            bv[n2] = __builtin_bit_cast(bf16x8,                                     \
                *(const ushort8v*)&lB[((wc * 4 + n2) * 4 + quad) * 128 + l16 * 8]); \
        asm volatile("s_waitcnt lgkmcnt(0)" ::: "memory");                          \
        __builtin_amdgcn_sched_barrier(0);                                          \
        __builtin_amdgcn_s_barrier();                                               \
        __builtin_amdgcn_sched_barrier(0);                                          \
        if (DOSTAGE_) STAGE((ks_) + 4, (b_));                                       \
        __builtin_amdgcn_s_setprio(1);                                              \
        _Pragma("unroll")                                                           \
        for (int m2 = 0; m2 < 4; m2++)                                              \
            _Pragma("unroll")                                                       \
            for (int n2 = 0; n2 < 4; n2++)                                          \
                acc[m2][n2] = __builtin_amdgcn_mfma_f32_16x16x32_bf16(              \
                    af[m2], bv[n2], acc[m2][n2], 0, 0, 0);                          \
        __builtin_amdgcn_s_setprio(0);                                              \
    }

template <int KC>
__global__ __launch_bounds__(256, 2) void gemm_p4(const unsigned short* __restrict__ A2,
                                                  const unsigned short* __restrict__ B2,
                                                  float* __restrict__ of32, int ldo) {
    __shared__ unsigned short lds[4][8192];

    const int tid  = threadIdx.x;
    const int lane = tid & 63;
    const int wave = tid >> 6;
    const int quad = lane >> 4, l16 = lane & 15;
    const int wr = wave >> 1, wc = wave & 1;

    const int bid = blockIdx.x;
    const int xcd = bid & 7;
    const int j   = bid >> 3;
    const int bm  = xcd * 8 + (j & 7);
    const int bn  = j >> 3;

    const int c0  = tid >> 4;
    const int sub = (tid & 15) * 8;
    const unsigned short* gA0 = A2 + ((size_t)(bm * 8 + (c0 >> 2))        * KC + (c0 & 3)) * 128 + sub;
    const unsigned short* gA1 = A2 + ((size_t)(bm * 8 + ((c0 + 16) >> 2)) * KC + (c0 & 3)) * 128 + sub;
    const unsigned short* gB0 = B2 + ((size_t)(bn * 8 + (c0 >> 2))        * KC + (c0 & 3)) * 128 + sub;
    const unsigned short* gB1 = B2 + ((size_t)(bn * 8 + ((c0 + 16) >> 2)) * KC + (c0 & 3)) * 128 + sub;
    const int dA0 = c0 * 128 + sub;
    const int dA1 = (c0 + 16) * 128 + sub;
    const int dB0 = 4096 + c0 * 128 + sub;
    const int dB1 = 4096 + (c0 + 16) * 128 + sub;

    floatx4 acc[4][4] = {};
    constexpr int nks = KC / 4;

    auto STAGE = [&](int ks, int b) {
        const size_t ko = (size_t)ks * 512;
        gload16(gA0 + ko, &lds[b][dA0]);
        gload16(gA1 + ko, &lds[b][dA1]);
        gload16(gB0 + ko, &lds[b][dB0]);
        gload16(gB1 + ko, &lds[b][dB1]);
    };

    STAGE(0, 0); STAGE(1, 1); STAGE(2, 2); STAGE(3, 3);

    for (int ks = 0; ks < nks - 4; ++ks) {
        P4_STEP(ks, ks & 3, 12, true);
    }
    P4_STEP(nks - 4, (nks - 4) & 3, 12, false);
    P4_STEP(nks - 3, (nks - 3) & 3, 8,  false);
    P4_STEP(nks - 2, (nks - 2) & 3, 4,  false);
    P4_STEP(nks - 1, (nks - 1) & 3, 0,  false);

    const int mt0 = bm * 8 + wr * 4;
    const int nt0 = bn * 8 + wc * 4;
#pragma unroll
    for (int n2 = 0; n2 < 4; n2++) {
        const int col = (nt0 + n2) * 16 + l16;
#pragma unroll
        for (int m2 = 0; m2 < 4; m2++) {
            const int row0 = (mt0 + m2) * 16 + quad * 4;
#pragma unroll
            for (int r = 0; r < 4; r++) {
                if (col < 1000) of32[(size_t)(row0 + r) * ldo + col] = acc[m2][n2][r];
            }
        }
    }
}

// ---------- host ----------
extern "C" void kernel_launch(void* const* d_in, const int* in_sizes, int n_in,
                              void* d_out, int out_size, void* d_ws, size_t ws_size,
                              hipStream_t stream) {
    const float* x   = (const float*)d_in[0];   // 8192x2048
    const float* W   = (const float*)d_in[1];   // 2048x1023
    const float* b   = (const float*)d_in[2];   // 1023
    const float* ldd = (const float*)d_in[3];   // 1024x1000
    float* out = (float*)d_out;                 // 8192x1000

    char* ws = (char*)d_ws;
    unsigned short* A2x = (unsigned short*)(ws);              // 33,554,432 B (swizzled x bf16)
    unsigned short* A2p = (unsigned short*)(ws);              // overlay: pp output (A2x dead by then)
    unsigned short* B2w = (unsigned short*)(ws + 33554432);   //  4,194,304 B (swizzled W^T)
    unsigned short* dec = (unsigned short*)(ws + 37748736);   // 16,777,216 B (row-major decisions)
    unsigned short* B2p = (unsigned short*)(ws + 54525952);   //  2,097,152 B (swizzled P^T)

    // prep: x-swizzle | W-transpose-swizzle | softmax->swizzle
    prep_kernel<<<5120, 256, 0, stream>>>(x, A2x, W, B2w, ldd, B2p);
    // decisions = sigmoid(x@W + b): 4-phase 256x128 BK=64 pipeline (race-fixed)
    gemm_m1<<<256, 512, 0, stream>>>(A2x, B2w, b, dec);
    // pp (reference-literal order), 8 rows/block, writes swizzled A2p
    pp_kernel<<<1024, 256, 0, stream>>>(dec, A2p);
    // out = pp @ P
    gemm_p4<128><<<512, 256, 0, stream>>>(A2p, B2p, out, 1000);
}

// Round 12
// 199.147 us; speedup vs baseline: 1.8754x; 1.0063x over previous
//
#include <hip/hip_runtime.h>

// ---------- common helpers ----------
typedef __attribute__((ext_vector_type(8))) unsigned short ushort8v;
typedef __attribute__((ext_vector_type(4))) unsigned short ushort4v;
typedef __attribute__((ext_vector_type(8))) __bf16 bf16x8;
typedef __attribute__((ext_vector_type(4))) float floatx4;

__device__ __forceinline__ unsigned short f2b(float f) {
    unsigned u = __float_as_uint(f);
    unsigned r = u + 0x7fffu + ((u >> 16) & 1u);   // RNE
    return (unsigned short)(r >> 16);
}
__device__ __forceinline__ float b2f(unsigned short h) {
    return __uint_as_float(((unsigned)h) << 16);
}
__device__ __forceinline__ void gload16(const void* g, void* l) {
    __builtin_amdgcn_global_load_lds(
        (const __attribute__((address_space(1))) unsigned int*)g,
        (__attribute__((address_space(3))) unsigned int*)l,
        16, 0, 0);
}

#define VMW(N) asm volatile("s_waitcnt vmcnt(" #N ")" ::: "memory")

// ============================================================================
// R20. R19 (race-fixed 4-phase) = 44.7us: SAME as R9/R11/R14 (45-47). Phase
// structure is null on this shape. Surviving cross-structure model: staged
// rate ≈ 1.8 B/cyc PER RESIDENT WAVE (8 waves/CU -> 13.8-14.6 measured here;
// m97/m103 at 12 waves -> 20.7-21.7). Only untried knob: waves/CU via BLOCK
// SIZE (grid is geometry-capped at 256, block size is not).
// gemm1 -> 256x128, 1024 threads = 16 waves (4Mx4N, 64x32/wave), same R14
// 3-buffer rotating counted-vmcnt skeleton {STAGE(k+2); VMW(6); barrier;
// ds_read; lgkmcnt(0); MFMA; barrier}, BK=64, 3 gload16/thread/step, tail
// 3/0. acc 4x2 (32 VGPR); per-kk frag reads keep VGPR ~90 (<=128 required
// for 16 waves/CU; launch_bounds(1024,4)). K-chain per output unchanged ->
// bitwise-identical. prep/pp/gemm2 R15 VERBATIM (already ~at floor).
// Predictions: model(a) per-wave concurrency -> ~24us; model(b) per-CU
// gload issue cap ~20B/cyc -> 32-36us. Null >= 42us -> declare roofline.
// Fragment-swizzled layout: tensor [T16][KC][16][8] bf16;
//   elem (t16, kc, l, e) = Mat[t16*16 + l][kc*8 + e]
// ============================================================================

// ---------- fused prep (R15 verbatim) ----------
__global__ __launch_bounds__(256) void prep_kernel(const float* __restrict__ x,
                                                   unsigned short* __restrict__ A2x,
                                                   const float* __restrict__ W,
                                                   unsigned short* __restrict__ B2w,
                                                   const float* __restrict__ ld_,
                                                   unsigned short* __restrict__ B2p) {
    __shared__ float tile[32 * 33];
    __shared__ float buf[1000];
    __shared__ float red[8];
    const int b = blockIdx.x, t = threadIdx.x;
    if (b < 2048) {                        // ---- cvt+swizzle x ----
        const int mt = b >> 2, kq = (b & 3) * 64;
        const int l16 = t >> 4;
        const int sg  = t & 15;
        const float* xr = x + (size_t)(mt * 16 + l16) * 2048 + (size_t)(kq + sg * 4) * 8;
#pragma unroll
        for (int c = 0; c < 4; c++) {
            float4 v0 = *(const float4*)(xr + c * 8);
            float4 v1 = *(const float4*)(xr + c * 8 + 4);
            ushort8v o;
            o[0] = f2b(v0.x); o[1] = f2b(v0.y); o[2] = f2b(v0.z); o[3] = f2b(v0.w);
            o[4] = f2b(v1.x); o[5] = f2b(v1.y); o[6] = f2b(v1.z); o[7] = f2b(v1.w);
            const int kc = kq + sg * 4 + c;
            *(ushort8v*)(A2x + ((size_t)(mt * 256 + kc) * 16 + l16) * 8) = o;
        }
    } else if (b < 4096) {                 // ---- transpose+swizzle W, ushort4 stores ----
        const int idx = b - 2048;
        const int n0 = (idx & 31) * 32, k0 = (idx >> 5) * 32;
        const int tx = t & 31, ty = t >> 5;
#pragma unroll
        for (int i = 0; i < 4; i++) {
            int k = k0 + ty + i * 8, n = n0 + tx;
            tile[(ty + i * 8) * 33 + tx] = (n < 1023) ? W[(size_t)k * 1023 + n] : 0.f;
        }
        __syncthreads();
        {
            const int tx2 = t & 31, ky = t >> 5;
            const int n = n0 + tx2;
            const int k = k0 + ky * 4;
            ushort4v o;
#pragma unroll
            for (int e = 0; e < 4; e++) o[e] = f2b(tile[(ky * 4 + e) * 33 + tx2]);
            size_t off = ((size_t)((n >> 4) * 256 + (k >> 3)) * 16 + (n & 15)) * 8 + (k & 7);
            *(ushort4v*)(B2w + off) = o;
        }
    } else {                               // ---- softmax -> B2p swizzled ----
        const int l0 = b - 4096;
        const float* r = ld_ + (size_t)l0 * 1000;
        float mx = -3.4e38f;
        for (int i = t; i < 1000; i += 256) { float v = r[i]; buf[i] = v; mx = fmaxf(mx, v); }
#pragma unroll
        for (int o = 32; o > 0; o >>= 1) mx = fmaxf(mx, __shfl_down(mx, o));
        if ((t & 63) == 0) red[t >> 6] = mx;
        __syncthreads();
        mx = fmaxf(fmaxf(red[0], red[1]), fmaxf(red[2], red[3]));
        float s = 0.f;
        for (int i = t; i < 1000; i += 256) { float e = __expf(buf[i] - mx); buf[i] = e; s += e; }
#pragma unroll
        for (int o = 32; o > 0; o >>= 1) s += __shfl_down(s, o);
        if ((t & 63) == 0) red[4 + (t >> 6)] = s;
        __syncthreads();
        float inv = 1.f / (red[4] + red[5] + red[6] + red[7]);
        for (int i = t; i < 1024; i += 256) {
            float pv = (i < 1000) ? buf[i] * inv : 0.f;
            size_t off = ((size_t)((i >> 4) * 128 + (l0 >> 3)) * 16 + (i & 15)) * 8 + (l0 & 7);
            B2p[off] = f2b(pv);
        }
    }
}

// ---------- pp: R15 verbatim ----------
__global__ __launch_bounds__(256) void pp_kernel(const unsigned short* __restrict__ dec,
                                                 unsigned short* __restrict__ A2p) {
    __shared__ unsigned short dsh[8 * 1024];
    __shared__ float pa[8 * 1024];
    __shared__ float pb[8 * 1024];
    const int t = threadIdx.x;
    const int r0 = blockIdx.x * 8;
    {
        const ushort8v* src = (const ushort8v*)(dec + (size_t)r0 * 1024);
        ushort8v* dst = (ushort8v*)dsh;
        for (int g = t; g < 1024; g += 256) dst[g] = src[g];
    }
    __syncthreads();
    {
        const int r  = t >> 5;
        const int jb = (t & 31) * 2;
        const unsigned short* dr = &dsh[r * 1024];
#pragma unroll
        for (int e = 0; e < 2; e++) {
            int idx = jb + e;
            float fac[6];
#pragma unroll
            for (int dep = 5; dep >= 0; --dep) {
                const int half = 1 << dep;
                const int tt = idx >> dep;
                const int s  = idx & (half - 1);
                const int i2 = 2 * s + tt;
                const int u  = i2 >> dep;
                const int rr = i2 & (half - 1);
                const float dv = b2f(dr[half - 1 + rr]);
                fac[dep] = u ? (1.f - dv) : dv;
                idx = rr;
            }
            float prod = fac[0];
#pragma unroll
            for (int dep = 1; dep < 6; dep++) prod *= fac[dep];
            pa[r * 1024 + jb + e] = prod;
        }
    }
    __syncthreads();
    float* cur = pa; float* nxt = pb;
    for (int dep = 6; dep < 10; dep++) {
        const int half = 1 << dep;
        const int len  = half << 1;
        const int total = len << 3;
        for (int idx = t; idx < total; idx += 256) {
            const int r = idx >> (dep + 1);
            const int j = idx & (len - 1);
            int tt = j >> dep;
            int s  = j & (half - 1);
            int i2 = 2 * s + tt;
            int u  = i2 >> dep;
            int rr = i2 & (half - 1);
            float dv = b2f(dsh[r * 1024 + half - 1 + rr]);
            nxt[r * 1024 + j] = cur[r * 1024 + rr] * (u ? (1.f - dv) : dv);
        }
        __syncthreads();
        float* tmp = cur; cur = nxt; nxt = tmp;
    }
    {
        const int r  = t >> 5;
        const int jb = (t & 31) * 32;
        const int rrow = r0 + r;
        const float* cr = &cur[r * 1024];
        const size_t rbase = (size_t)(rrow >> 4) * 128 * 128 + (size_t)(rrow & 15) * 8;
#pragma unroll
        for (int g = 0; g < 8; g++) {
            const int j = jb + g * 4;
            ushort4v o;
            o[0] = f2b(cr[j]); o[1] = f2b(cr[j + 1]);
            o[2] = f2b(cr[j + 2]); o[3] = f2b(cr[j + 3]);
            size_t off = rbase + (size_t)(j >> 3) * 128 + (j & 7);
            *(ushort4v*)(A2p + off) = o;
        }
    }
}

// ---------- gemm1: 256x128, 1024 thr = 16 waves, 3 rotating bufs, counted vmcnt ----------
// Buffer (48KB ushorts[24576]): A = 16 slabs x 8 kc-chunks = 128 chunks (32KB)
// at [0..16384), B = 8 slabs x 8 chunks (16KB) at [16384..24576).
// Stage = 3 gload16/thread/step (A 2 rounds, B 1); LDS dest = t*16B (linear).
// Step: STAGE(k+2); VMW(6); s_barrier; per-kk {6 ds_read_b128; lgkmcnt(0);
// setprio(1); 8 MFMA; setprio(0)}; s_barrier. Tail VMW 3/0.
#define R16A(m2_, kk_) __builtin_bit_cast(bf16x8, \
    *(const ushort8v*)&lA[((wr * 4 + (m2_)) * 8 + (kk_) * 4 + quad) * 128 + l16 * 8])
#define R16B(n2_, kk_) __builtin_bit_cast(bf16x8, \
    *(const ushort8v*)&lB[((wc * 2 + (n2_)) * 8 + (kk_) * 4 + quad) * 128 + l16 * 8])
#define MM16(AV_, m2_, n2_, BV_) acc[m2_][n2_] = \
    __builtin_amdgcn_mfma_f32_16x16x32_bf16(AV_, BV_, acc[m2_][n2_], 0, 0, 0);

#define M16_STEP(ks_, CUR_, STG_, VM_, DOSTAGE_)                                  \
    {                                                                             \
        if (DOSTAGE_) STAGE((ks_) + 2, (STG_));                                   \
        VMW(VM_);                                                                 \
        __builtin_amdgcn_s_barrier();                                             \
        const unsigned short* lA = &lds[(CUR_)][0];                               \
        const unsigned short* lB = &lds[(CUR_)][16384];                           \
        _Pragma("unroll")                                                         \
        for (int kk = 0; kk < 2; kk++) {                                          \
            bf16x8 a0 = R16A(0, kk), a1 = R16A(1, kk);                            \
            bf16x8 a2 = R16A(2, kk), a3 = R16A(3, kk);                            \
            bf16x8 b0 = R16B(0, kk), b1 = R16B(1, kk);                            \
            asm volatile("s_waitcnt lgkmcnt(0)" ::: "memory");                    \
            __builtin_amdgcn_sched_barrier(0);                                    \
            __builtin_amdgcn_s_setprio(1);                                        \
            MM16(a0, 0, 0, b0) MM16(a0, 0, 1, b1)                                 \
            MM16(a1, 1, 0, b0) MM16(a1, 1, 1, b1)                                 \
            MM16(a2, 2, 0, b0) MM16(a2, 2, 1, b1)                                 \
            MM16(a3, 3, 0, b0) MM16(a3, 3, 1, b1)                                 \
            __builtin_amdgcn_s_setprio(0);                                        \
        }                                                                         \
        __builtin_amdgcn_s_barrier();                                             \
    }

__global__ __launch_bounds__(1024, 4) void gemm_m1(const unsigned short* __restrict__ A2,
                                                   const unsigned short* __restrict__ B2,
                                                   const float* __restrict__ bias,
                                                   unsigned short* __restrict__ obf) {
    constexpr int KC = 256;                    // total kc-chunks over K=2048
    __shared__ unsigned short lds[3][24576];   // 3 x 48KB = 144KB -> 1 block/CU

    const int t    = threadIdx.x;              // 0..1023
    const int lane = t & 63;
    const int wave = t >> 6;                   // 0..15
    const int quad = lane >> 4, l16 = lane & 15;
    const int wr = wave >> 2, wc = wave & 3;   // 4M x 4N wave grid, 64x32/wave

    const int bid = blockIdx.x;                // 256 blocks = 1/CU, 16 waves/CU
    const int xcd = bid & 7;
    const int j   = bid >> 3;                  // 0..31
    const int bm  = xcd * 4 + (j & 3);         // 0..31 (256-row tiles)
    const int bn  = j >> 2;                    // 0..7  (128-col tiles)

    // stage map: A round i covers chunks c = i*64 + (t>>4); slab=c>>3, kcq=c&7;
    // B covers chunk c = t>>4. LDS dest = t*16B + i*16KB (linear, legal).
    const int cT  = t >> 4;                    // 0..63
    const int sub = (t & 15) * 8;
    const unsigned short* gA[2];
#pragma unroll
    for (int i = 0; i < 2; i++) {
        const int c = i * 64 + cT;
        gA[i] = A2 + ((size_t)(bm * 16 + (c >> 3)) * KC + (c & 7)) * 128 + sub;
    }
    const unsigned short* gB0 = B2 + ((size_t)(bn * 8 + (cT >> 3)) * KC + (cT & 7)) * 128 + sub;
    const int dA = t * 8;                      // ushort offset (= t*16 B)
    const int dB = 16384 + t * 8;

    floatx4 acc[4][2] = {};
    constexpr int nks = 32;                    // BK=64 -> 8 kc-chunks/step

    auto STAGE = [&](int ks, int b) {
        const size_t ko = (size_t)ks * 1024;   // 8 kc-chunks * 128 ushorts
        gload16(gA[0] + ko, &lds[b][dA]);
        gload16(gA[1] + ko, &lds[b][8192 + dA]);
        gload16(gB0 + ko, &lds[b][dB]);
    };

    // prologue: depth-2 prefetch
    STAGE(0, 0); STAGE(1, 1);

    int c0 = 0, c1 = 1, c2 = 2;
    for (int ks = 0; ks < nks - 2; ++ks) {
        M16_STEP(ks, c0, c2, 6, true);
        int tmp = c0; c0 = c1; c1 = c2; c2 = tmp;
    }
    M16_STEP(nks - 2, c0, c2, 3, false);
    { int tmp = c0; c0 = c1; c1 = c2; c2 = tmp; }
    M16_STEP(nks - 1, c0, c2, 0, false);

    // ---- epilogue: sigmoid(acc + bias[col]) -> bf16, ldo=1024 ----
    const int mt0 = bm * 16 + wr * 4;
    const int nt0 = bn * 8  + wc * 2;
#pragma unroll
    for (int n2 = 0; n2 < 2; n2++) {
        const int col = (nt0 + n2) * 16 + l16;
        const float bbias = (col < 1023) ? bias[col] : 0.f;
#pragma unroll
        for (int m2 = 0; m2 < 4; m2++) {
            const int row0 = (mt0 + m2) * 16 + quad * 4;
#pragma unroll
            for (int r = 0; r < 4; r++) {
                float sgm = 1.f / (1.f + __expf(-(acc[m2][n2][r] + bbias)));
                obf[(size_t)(row0 + r) * 1024 + col] = f2b(sgm);
            }
        }
    }
}

// ---------- gemm2: R15 verbatim (128x128, 4 waves, 4 buffers, counted vmcnt) ----------
#define P4_STEP(ks_, b_, VM_, DOSTAGE_)                                             \
    {                                                                               \
        VMW(VM_);                                                                   \
        __builtin_amdgcn_s_barrier();                                               \
        __builtin_amdgcn_sched_barrier(0);                                          \
        const unsigned short* lA = &lds[(b_)][0];                                   \
        const unsigned short* lB = &lds[(b_)][4096];                                \
        bf16x8 af[4], bv[4];                                                        \
        _Pragma("unroll")                                                           \
        for (int m2 = 0; m2 < 4; m2++)                                              \
            af[m2] = __builtin_bit_cast(bf16x8,                                     \
                *(const ushort8v*)&lA[((wr * 4 + m2) * 4 + quad) * 128 + l16 * 8]); \
        _Pragma("unroll")                                                           \
        for (int n2 = 0; n2 < 4; n2++)                                              \
            bv[n2] = __builtin_bit_cast(bf16x8,                                     \
                *(const ushort8v*)&lB[((wc * 4 + n2) * 4 + quad) * 128 + l16 * 8]); \
        asm volatile("s_waitcnt lgkmcnt(0)" ::: "memory");                          \
        __builtin_amdgcn_sched_barrier(0);                                          \
        __builtin_amdgcn_s_barrier();                                               \
        __builtin_amdgcn_sched_barrier(0);                                          \
        if (DOSTAGE_) STAGE((ks_) + 4, (b_));                                       \
        __builtin_amdgcn_s_setprio(1);                                              \
        _Pragma("unroll")                                                           \
        for (int m2 = 0; m2 < 4; m2++)                                              \
            _Pragma("unroll")                                                       \
            for (int n2 = 0; n2 < 4; n2++)                                          \
                acc[m2][n2] = __builtin_amdgcn_mfma_f32_16x16x32_bf16(              \
                    af[m2], bv[n2], acc[m2][n2], 0, 0, 0);                          \
        __builtin_amdgcn_s_setprio(0);                                              \
    }

template <int KC>
__global__ __launch_bounds__(256, 2) void gemm_p4(const unsigned short* __restrict__ A2,
                                                  const unsigned short* __restrict__ B2,
                                                  float* __restrict__ of32, int ldo) {
    __shared__ unsigned short lds[4][8192];

    const int tid  = threadIdx.x;
    const int lane = tid & 63;
    const int wave = tid >> 6;
    const int quad = lane >> 4, l16 = lane & 15;
    const int wr = wave >> 1, wc = wave & 1;

    const int bid = blockIdx.x;
    const int xcd = bid & 7;
    const int j   = bid >> 3;
    const int bm  = xcd * 8 + (j & 7);
    const int bn  = j >> 3;

    const int c0  = tid >> 4;
    const int sub = (tid & 15) * 8;
    const unsigned short* gA0 = A2 + ((size_t)(bm * 8 + (c0 >> 2))        * KC + (c0 & 3)) * 128 + sub;
    const unsigned short* gA1 = A2 + ((size_t)(bm * 8 + ((c0 + 16) >> 2)) * KC + (c0 & 3)) * 128 + sub;
    const unsigned short* gB0 = B2 + ((size_t)(bn * 8 + (c0 >> 2))        * KC + (c0 & 3)) * 128 + sub;
    const unsigned short* gB1 = B2 + ((size_t)(bn * 8 + ((c0 + 16) >> 2)) * KC + (c0 & 3)) * 128 + sub;
    const int dA0 = c0 * 128 + sub;
    const int dA1 = (c0 + 16) * 128 + sub;
    const int dB0 = 4096 + c0 * 128 + sub;
    const int dB1 = 4096 + (c0 + 16) * 128 + sub;

    floatx4 acc[4][4] = {};
    constexpr int nks = KC / 4;

    auto STAGE = [&](int ks, int b) {
        const size_t ko = (size_t)ks * 512;
        gload16(gA0 + ko, &lds[b][dA0]);
        gload16(gA1 + ko, &lds[b][dA1]);
        gload16(gB0 + ko, &lds[b][dB0]);
        gload16(gB1 + ko, &lds[b][dB1]);
    };

    STAGE(0, 0); STAGE(1, 1); STAGE(2, 2); STAGE(3, 3);

    for (int ks = 0; ks < nks - 4; ++ks) {
        P4_STEP(ks, ks & 3, 12, true);
    }
    P4_STEP(nks - 4, (nks - 4) & 3, 12, false);
    P4_STEP(nks - 3, (nks - 3) & 3, 8,  false);
    P4_STEP(nks - 2, (nks - 2) & 3, 4,  false);
    P4_STEP(nks - 1, (nks - 1) & 3, 0,  false);

    const int mt0 = bm * 8 + wr * 4;
    const int nt0 = bn * 8 + wc * 4;
#pragma unroll
    for (int n2 = 0; n2 < 4; n2++) {
        const int col = (nt0 + n2) * 16 + l16;
#pragma unroll
        for (int m2 = 0; m2 < 4; m2++) {
            const int row0 = (mt0 + m2) * 16 + quad * 4;
#pragma unroll
            for (int r = 0; r < 4; r++) {
                if (col < 1000) of32[(size_t)(row0 + r) * ldo + col] = acc[m2][n2][r];
            }
        }
    }
}

// ---------- host ----------
extern "C" void kernel_launch(void* const* d_in, const int* in_sizes, int n_in,
                              void* d_out, int out_size, void* d_ws, size_t ws_size,
                              hipStream_t stream) {
    const float* x   = (const float*)d_in[0];   // 8192x2048
    const float* W   = (const float*)d_in[1];   // 2048x1023
    const float* b   = (const float*)d_in[2];   // 1023
    const float* ldd = (const float*)d_in[3];   // 1024x1000
    float* out = (float*)d_out;                 // 8192x1000

    char* ws = (char*)d_ws;
    unsigned short* A2x = (unsigned short*)(ws);              // 33,554,432 B (swizzled x bf16)
    unsigned short* A2p = (unsigned short*)(ws);              // overlay: pp output (A2x dead by then)
    unsigned short* B2w = (unsigned short*)(ws + 33554432);   //  4,194,304 B (swizzled W^T)
    unsigned short* dec = (unsigned short*)(ws + 37748736);   // 16,777,216 B (row-major decisions)
    unsigned short* B2p = (unsigned short*)(ws + 54525952);   //  2,097,152 B (swizzled P^T)

    // prep: x-swizzle | W-transpose-swizzle | softmax->swizzle
    prep_kernel<<<5120, 256, 0, stream>>>(x, A2x, W, B2w, ldd, B2p);
    // decisions = sigmoid(x@W + b): 16-wave 256x128 BK=64 pipeline
    gemm_m1<<<256, 1024, 0, stream>>>(A2x, B2w, b, dec);
    // pp (reference-literal order), 8 rows/block, writes swizzled A2p
    pp_kernel<<<1024, 256, 0, stream>>>(dec, A2p);
    // out = pp @ P
    gemm_p4<128><<<512, 256, 0, stream>>>(A2p, B2p, out, 1000);
}